// Round 6
// baseline (581.191 us; speedup 1.0000x reference)
//
#include <hip/hip_runtime.h>
#include <hip/hip_cooperative_groups.h>

namespace cg = cooperative_groups;

typedef __bf16 bf16;
typedef bf16 bf16x4 __attribute__((ext_vector_type(4)));
typedef bf16 bf16x8 __attribute__((ext_vector_type(8)));
typedef float f32x4 __attribute__((ext_vector_type(4)));

#define NB 4
#define NC 256
#define ND 32
#define NN 4096
#define SPL 4      // n-split (attn) / m-split (rowsum)
#define GRID 512   // 2 blocks/CU — safe margin for cooperative co-residency
#define VUNITS 2   // virtual units per block per phase (GRID*VUNITS = 1024)

// ===========================================================================
// Mega kernel: 4 phases with grid.sync() between. 512 blocks x 256 threads,
// each block handles 2 virtual work units per phase (vbid = u*512 + bid).
//  A: f/g/h = W@x -> fT,gT [B][N][D], hM [B][D][N] (bf16); W converted inline
//  B: Lpart[ms][b][n] = partial sum_m exp(S[n,m])
//  C: saWS[ns][b][m][d] = partial sum_n h[d,n]*exp(S[n,m])/L[n]
//  D: out[c,m] = gamma*(Wv . sa + bv)
// ===========================================================================
__global__ __launch_bounds__(256, 2) void k_mega(
    const float* __restrict__ x,
    const float* __restrict__ Wf, const float* __restrict__ bfp,
    const float* __restrict__ Wg, const float* __restrict__ bgp,
    const float* __restrict__ Wh, const float* __restrict__ bhp,
    const float* __restrict__ Wv, const float* __restrict__ bv,
    const float* __restrict__ gamma,
    bf16* __restrict__ fT, bf16* __restrict__ gT, bf16* __restrict__ hM,
    float* __restrict__ Lpart, float* __restrict__ saWS,
    float* __restrict__ out)
{
    __shared__ __align__(16) char smem[18432];
    cg::grid_group grid = cg::this_grid();

    const int bid  = blockIdx.x;
    const int t    = threadIdx.x;
    const int lane = t & 63;
    const int w    = t >> 6;
    const int l15  = lane & 15;
    const int l4   = lane >> 4;

    // ======================= Phase A: f/g/h projections ====================
    for (int u = 0; u < VUNITS; ++u) {
        __syncthreads();                     // guard LDS WAR across units
        const int vbid = (u << 9) | bid;
        const int b    = vbid >> 8;
        const int rest = vbid & 255;
        const int n0   = (rest >> 1) * 32;   // 128 n-tiles of 32
        const int half = rest & 1;           // row-tiles 3*half .. 3*half+2
        char* xb = smem;                     // [32 n][512 B] bf16, XOR-swizzled

        {
            const int nl  = t & 31;
            const int swz = (nl & 7) << 4;
            const int chi = (t >> 5) * 8;    // 0..56
            #pragma unroll
            for (int pass = 0; pass < 4; ++pass) {
                int c0 = pass * 64 + chi;
                const float* xp = x + ((size_t)b * NC + c0) * NN + n0 + nl;
                bf16x8 v;
                #pragma unroll
                for (int j = 0; j < 8; ++j) v[j] = (bf16)xp[(size_t)j * NN];
                *reinterpret_cast<bf16x8*>(&xb[nl * 512 + ((c0 * 2) ^ swz)]) = v;
            }
        }
        __syncthreads();

        #pragma unroll
        for (int rep = 0; rep < 2; ++rep) {
            int tk = w + 4 * rep;            // 6 tasks (strip x row-tile)
            if (tk < 6) {
                const int strip  = tk & 1;
                const int rt     = half * 3 + (tk >> 1);   // 0..5
                const int tensor = rt >> 1;                // 0 f, 1 g, 2 h
                const float* Wsel = tensor == 0 ? Wf : tensor == 1 ? Wg : Wh;
                const float* bsel = tensor == 0 ? bfp : tensor == 1 ? bgp : bhp;
                const int drow = (rt & 1) * 16 + l15;      // row within tensor
                const int ncol = strip * 16 + l15;
                const int nswz = (ncol & 7) << 4;
                f32x4 acc = {0.f, 0.f, 0.f, 0.f};
                #pragma unroll
                for (int kc = 0; kc < 8; ++kc) {
                    const float* wp = Wsel + drow * NC + kc * 32 + l4 * 8;
                    f32x4 wlo = *reinterpret_cast<const f32x4*>(wp);
                    f32x4 whi = *reinterpret_cast<const f32x4*>(wp + 4);
                    bf16x8 a;
                    #pragma unroll
                    for (int j = 0; j < 4; ++j) {
                        a[j]     = (bf16)wlo[j];
                        a[4 + j] = (bf16)whi[j];
                    }
                    bf16x8 bb = *reinterpret_cast<const bf16x8*>(
                        &xb[ncol * 512 + ((kc * 64 + l4 * 16) ^ nswz)]);
                    acc = __builtin_amdgcn_mfma_f32_16x16x32_bf16(a, bb, acc, 0, 0, 0);
                }
                const int dbase = (rt & 1) * 16 + l4 * 4;
                const int n = n0 + ncol;
                if (tensor < 2) {
                    bf16x4 vv;
                    #pragma unroll
                    for (int r = 0; r < 4; ++r) vv[r] = (bf16)(acc[r] + bsel[dbase + r]);
                    bf16* dst = (tensor == 0 ? fT : gT) + ((size_t)b * NN + n) * ND + dbase;
                    *reinterpret_cast<bf16x4*>(dst) = vv;
                } else {
                    #pragma unroll
                    for (int r = 0; r < 4; ++r)
                        hM[((size_t)b * ND + dbase + r) * NN + n] =
                            (bf16)(acc[r] + bsel[dbase + r]);
                }
            }
        }
    }
    __threadfence();
    grid.sync();

    // ======================= Phase B: rowsum partials ======================
    for (int u = 0; u < VUNITS; ++u) {
        const int vbid = (u << 9) | bid;
        const int b  = vbid >> 8;
        const int r_ = vbid & 255;
        const int nb = (r_ >> 2) * 64;
        const int ms = r_ & 3;

        bf16x8 a = *reinterpret_cast<const bf16x8*>(
            fT + ((size_t)b * NN + nb + w * 16 + l15) * ND + l4 * 8);
        float sum0 = 0.f, sum1 = 0.f, sum2 = 0.f, sum3 = 0.f;
        const bf16* gp = gT + (size_t)b * NN * ND
                       + ((size_t)ms * (NN / SPL) + l15) * ND + l4 * 8;
        #pragma unroll 4
        for (int m = 0; m < NN / SPL; m += 32) {
            bf16x8 b0 = *reinterpret_cast<const bf16x8*>(gp + (size_t)m * ND);
            bf16x8 b1 = *reinterpret_cast<const bf16x8*>(gp + (size_t)(m + 16) * ND);
            f32x4 z = {0.f, 0.f, 0.f, 0.f};
            f32x4 s0 = __builtin_amdgcn_mfma_f32_16x16x32_bf16(a, b0, z, 0, 0, 0);
            f32x4 s1 = __builtin_amdgcn_mfma_f32_16x16x32_bf16(a, b1, z, 0, 0, 0);
            sum0 += __expf(s0[0]) + __expf(s1[0]);
            sum1 += __expf(s0[1]) + __expf(s1[1]);
            sum2 += __expf(s0[2]) + __expf(s1[2]);
            sum3 += __expf(s0[3]) + __expf(s1[3]);
        }
        float sv[4] = {sum0, sum1, sum2, sum3};
        #pragma unroll
        for (int r = 0; r < 4; ++r) {
            float v = sv[r];
            v += __shfl_xor(v, 1);
            v += __shfl_xor(v, 2);
            v += __shfl_xor(v, 4);
            v += __shfl_xor(v, 8);
            sv[r] = v;
        }
        if (l15 == 0) {
            #pragma unroll
            for (int r = 0; r < 4; ++r)
                Lpart[((size_t)ms * NB + b) * NN + nb + w * 16 + l4 * 4 + r] = sv[r];
        }
    }
    __threadfence();
    grid.sync();

    // ======================= Phase C: attention partials ===================
    for (int u = 0; u < VUNITS; ++u) {
        char* fL  = smem;                 // [64 n][80 B]
        char* hL  = smem + 5120;          // [32 d][144 B]
        char* Pl  = smem + 9728;          // 4 x 2048 per-wave
        float* rlL = (float*)(smem + 17920); // [64]

        const int vbid = (u << 9) | bid;
        const int b  = vbid >> 8;
        const int r_ = vbid & 255;
        const int m0 = (r_ >> 2) * 64;
        const int ns = r_ & 3;

        bf16x8 gfrag = *reinterpret_cast<const bf16x8*>(
            gT + ((size_t)b * NN + m0 + w * 16 + l15) * ND + l4 * 8);

        f32x4 acc0 = {0.f, 0.f, 0.f, 0.f};
        f32x4 acc1 = {0.f, 0.f, 0.f, 0.f};

        char* Pw = &Pl[w * 2048];
        const int mswz = (l15 & 7) << 4;

        const int s_nl = t >> 2;
        const int s_dl = (t & 3) * 8;
        const int s_d  = t >> 3;
        const int s_ne = (t & 7) * 8;
        const bf16* fsrc = fT + (size_t)b * NN * ND;
        const bf16* hsrc = hM + (size_t)b * ND * NN;

        const int nbeg = ns * (NN / SPL);
        const int nend = nbeg + NN / SPL;

        for (int n1 = nbeg; n1 < nend; n1 += 64) {
            __syncthreads();
            *reinterpret_cast<bf16x8*>(&fL[s_nl * 80 + s_dl * 2]) =
                *reinterpret_cast<const bf16x8*>(fsrc + (size_t)(n1 + s_nl) * ND + s_dl);
            *reinterpret_cast<bf16x8*>(&hL[s_d * 144 + s_ne * 2]) =
                *reinterpret_cast<const bf16x8*>(hsrc + (size_t)s_d * NN + n1 + s_ne);
            if (t < 64) {
                float s = 0.f;
                #pragma unroll
                for (int ms = 0; ms < SPL; ++ms)
                    s += Lpart[((size_t)ms * NB + b) * NN + n1 + t];
                rlL[t] = 1.0f / s;
            }
            __syncthreads();

            #pragma unroll
            for (int nt = 0; nt < 4; ++nt) {
                bf16x8 afrag = *reinterpret_cast<const bf16x8*>(
                    &fL[(nt * 16 + l15) * 80 + l4 * 16]);
                f32x4 z = {0.f, 0.f, 0.f, 0.f};
                f32x4 s = __builtin_amdgcn_mfma_f32_16x16x32_bf16(afrag, gfrag, z, 0, 0, 0);
                bf16x4 p4;
                #pragma unroll
                for (int r = 0; r < 4; ++r)
                    p4[r] = (bf16)(__expf(s[r]) * rlL[nt * 16 + l4 * 4 + r]);
                *reinterpret_cast<bf16x4*>(
                    &Pw[l15 * 128 + ((nt * 32 + l4 * 8) ^ mswz)]) = p4;
            }
            #pragma unroll
            for (int kc = 0; kc < 2; ++kc) {
                bf16x8 pb = *reinterpret_cast<const bf16x8*>(
                    &Pw[l15 * 128 + ((kc * 64 + l4 * 16) ^ mswz)]);
                bf16x8 h0 = *reinterpret_cast<const bf16x8*>(
                    &hL[l15 * 144 + kc * 64 + l4 * 16]);
                acc0 = __builtin_amdgcn_mfma_f32_16x16x32_bf16(h0, pb, acc0, 0, 0, 0);
                bf16x8 h1 = *reinterpret_cast<const bf16x8*>(
                    &hL[(16 + l15) * 144 + kc * 64 + l4 * 16]);
                acc1 = __builtin_amdgcn_mfma_f32_16x16x32_bf16(h1, pb, acc1, 0, 0, 0);
            }
        }

        float* sp = saWS + (((size_t)ns * NB + b) * NN + m0 + w * 16 + l15) * ND;
        *reinterpret_cast<f32x4*>(sp + l4 * 4)      = acc0;
        *reinterpret_cast<f32x4*>(sp + 16 + l4 * 4) = acc1;
    }
    __threadfence();
    grid.sync();

    // ======================= Phase D: reduce + projection ==================
    for (int u = 0; u < VUNITS; ++u) {
        __syncthreads();                  // guard LDS WAR across units
        float* sa_s = (float*)smem;       // [64 m][33]
        const int vbid = (u << 9) | bid;
        const int b  = vbid >> 8;
        const int r_ = vbid & 255;
        const int m0 = (r_ >> 2) * 64;
        const int c0 = (r_ & 3) * 64;

        #pragma unroll
        for (int p = t; p < 64 * 8; p += 256) {
            int m = p >> 3, dq = (p & 7) * 4;
            float s0 = 0.f, s1 = 0.f, s2 = 0.f, s3 = 0.f;
            #pragma unroll
            for (int s4 = 0; s4 < SPL; ++s4) {
                f32x4 v = *reinterpret_cast<const f32x4*>(
                    saWS + (((size_t)s4 * NB + b) * NN + m0 + m) * ND + dq);
                s0 += v[0]; s1 += v[1]; s2 += v[2]; s3 += v[3];
            }
            float* dp = &sa_s[m * 33 + dq];
            dp[0] = s0; dp[1] = s1; dp[2] = s2; dp[3] = s3;
        }
        __syncthreads();

        const int mloc = t & 63;
        const int cg_  = t >> 6;          // wave-uniform c-group
        float sav[32];
        #pragma unroll
        for (int d = 0; d < 32; ++d) sav[d] = sa_s[mloc * 33 + d];
        const float g0 = gamma[0];
        float* op = out + (size_t)b * NC * NN + m0 + mloc;
        #pragma unroll
        for (int i = 0; i < 16; ++i) {
            int c = c0 + cg_ * 16 + i;
            const float* wp = Wv + c * ND;
            float sum = bv[c];
            #pragma unroll
            for (int d = 0; d < 32; ++d) sum = fmaf(wp[d], sav[d], sum);
            op[(size_t)c * NN] = g0 * sum;
        }
    }
}

// ===========================================================================
// Fallback pipeline (proven R2 kernels) — used only if cooperative launch
// is rejected by the runtime. Deterministic per call.
// ===========================================================================
__global__ __launch_bounds__(256) void k_wcvt(
    const float* __restrict__ Wf, const float* __restrict__ Wg,
    const float* __restrict__ Wh, bf16* __restrict__ Wstk)
{
    int e0 = (blockIdx.x * 256 + threadIdx.x) * 8;
    int row = e0 >> 8;
    int tensor = row >> 5;
    const float* src = tensor == 0 ? Wf : tensor == 1 ? Wg : Wh;
    const float* sp = src + (row & 31) * NC + (e0 & 255);
    bf16x8 v;
    #pragma unroll
    for (int j = 0; j < 8; ++j) v[j] = (bf16)sp[j];
    *reinterpret_cast<bf16x8*>(Wstk + e0) = v;
}

__global__ __launch_bounds__(512) void k_fgh(
    const float* __restrict__ x, const bf16* __restrict__ Wstk,
    const float* __restrict__ bfp, const float* __restrict__ bgp,
    const float* __restrict__ bhp,
    bf16* __restrict__ fT, bf16* __restrict__ gT, bf16* __restrict__ hM)
{
    __shared__ __align__(16) char xb[64 * 512];
    const int b  = blockIdx.y;
    const int n0 = blockIdx.x * 64;
    const int t  = threadIdx.x;
    const int lane = t & 63;
    const int w  = t >> 6;
    const int l15 = lane & 15;
    const int l4  = lane >> 4;
    {
        const int nl  = t & 63;
        const int swz = (nl & 7) << 4;
        const int chi = (t >> 6) * 8;
        #pragma unroll
        for (int pass = 0; pass < 4; ++pass) {
            int c0 = pass * 64 + chi;
            const float* xp = x + ((size_t)b * NC + c0) * NN + n0 + nl;
            bf16x8 v;
            #pragma unroll
            for (int j = 0; j < 8; ++j) v[j] = (bf16)xp[(size_t)j * NN];
            *reinterpret_cast<bf16x8*>(&xb[nl * 512 + ((c0 * 2) ^ swz)]) = v;
        }
    }
    __syncthreads();
    const int ncol = (w & 3) * 16 + l15;
    const int nswz = (ncol & 7) << 4;
    const int n    = n0 + ncol;
    const int dsub = l4 * 4;
    const int rtb  = (w >> 2) * 3;
    #pragma unroll
    for (int rr = 0; rr < 3; ++rr) {
        int rt = rtb + rr;
        int tensor = rt >> 1;
        int d0 = (rt & 1) * 16;
        f32x4 acc = {0.f, 0.f, 0.f, 0.f};
        #pragma unroll
        for (int kc = 0; kc < 8; ++kc) {
            bf16x8 a = *reinterpret_cast<const bf16x8*>(
                Wstk + (rt * 16 + l15) * NC + kc * 32 + l4 * 8);
            bf16x8 bb = *reinterpret_cast<const bf16x8*>(
                &xb[ncol * 512 + ((kc * 64 + l4 * 16) ^ nswz)]);
            acc = __builtin_amdgcn_mfma_f32_16x16x32_bf16(a, bb, acc, 0, 0, 0);
        }
        const float* bsel = tensor == 0 ? bfp : tensor == 1 ? bgp : bhp;
        int dbase = d0 + dsub;
        if (tensor < 2) {
            bf16x4 vv;
            #pragma unroll
            for (int r = 0; r < 4; ++r) vv[r] = (bf16)(acc[r] + bsel[dbase + r]);
            bf16* dst = (tensor == 0 ? fT : gT) + ((size_t)b * NN + n) * ND + dbase;
            *reinterpret_cast<bf16x4*>(dst) = vv;
        } else {
            #pragma unroll
            for (int r = 0; r < 4; ++r)
                hM[((size_t)b * ND + dbase + r) * NN + n] =
                    (bf16)(acc[r] + bsel[dbase + r]);
        }
    }
}

__global__ __launch_bounds__(256) void k_rowsum(
    const bf16* __restrict__ fT, const bf16* __restrict__ gT,
    float* __restrict__ Lpart)
{
    const int b  = blockIdx.z;
    const int ms = blockIdx.y;
    const int nb = blockIdx.x * 64;
    const int t  = threadIdx.x;
    const int lane = t & 63;
    const int w  = t >> 6;
    const int l15 = lane & 15;
    const int l4  = lane >> 4;
    bf16x8 a = *reinterpret_cast<const bf16x8*>(
        fT + ((size_t)b * NN + nb + w * 16 + l15) * ND + l4 * 8);
    float sum0 = 0.f, sum1 = 0.f, sum2 = 0.f, sum3 = 0.f;
    const bf16* gp = gT + (size_t)b * NN * ND
                   + ((size_t)ms * (NN / SPL) + l15) * ND + l4 * 8;
    #pragma unroll 4
    for (int m = 0; m < NN / SPL; m += 32) {
        bf16x8 b0 = *reinterpret_cast<const bf16x8*>(gp + (size_t)m * ND);
        bf16x8 b1 = *reinterpret_cast<const bf16x8*>(gp + (size_t)(m + 16) * ND);
        f32x4 z = {0.f, 0.f, 0.f, 0.f};
        f32x4 s0 = __builtin_amdgcn_mfma_f32_16x16x32_bf16(a, b0, z, 0, 0, 0);
        f32x4 s1 = __builtin_amdgcn_mfma_f32_16x16x32_bf16(a, b1, z, 0, 0, 0);
        sum0 += __expf(s0[0]) + __expf(s1[0]);
        sum1 += __expf(s0[1]) + __expf(s1[1]);
        sum2 += __expf(s0[2]) + __expf(s1[2]);
        sum3 += __expf(s0[3]) + __expf(s1[3]);
    }
    float sv[4] = {sum0, sum1, sum2, sum3};
    #pragma unroll
    for (int r = 0; r < 4; ++r) {
        float v = sv[r];
        v += __shfl_xor(v, 1);
        v += __shfl_xor(v, 2);
        v += __shfl_xor(v, 4);
        v += __shfl_xor(v, 8);
        sv[r] = v;
    }
    if (l15 == 0) {
        #pragma unroll
        for (int r = 0; r < 4; ++r)
            Lpart[((size_t)ms * NB + b) * NN + nb + w * 16 + l4 * 4 + r] = sv[r];
    }
}

__global__ __launch_bounds__(256) void k_attn(
    const bf16* __restrict__ fT, const bf16* __restrict__ gT,
    const bf16* __restrict__ hM, const float* __restrict__ Lpart,
    float* __restrict__ saWS)
{
    __shared__ __align__(16) char fL[64 * 80];
    __shared__ __align__(16) char hL[32 * 144];
    __shared__ __align__(16) char Pl[4 * 2048];
    __shared__ float rlL[64];
    const int b  = blockIdx.z;
    const int ns = blockIdx.y;
    const int m0 = blockIdx.x * 64;
    const int t  = threadIdx.x;
    const int lane = t & 63;
    const int w  = t >> 6;
    const int l15 = lane & 15;
    const int l4  = lane >> 4;
    bf16x8 gfrag = *reinterpret_cast<const bf16x8*>(
        gT + ((size_t)b * NN + m0 + w * 16 + l15) * ND + l4 * 8);
    f32x4 acc0 = {0.f, 0.f, 0.f, 0.f};
    f32x4 acc1 = {0.f, 0.f, 0.f, 0.f};
    char* Pw = &Pl[w * 2048];
    const int mswz = (l15 & 7) << 4;
    const int s_nl = t >> 2;
    const int s_dl = (t & 3) * 8;
    const int s_d  = t >> 3;
    const int s_ne = (t & 7) * 8;
    const bf16* fsrc = fT + (size_t)b * NN * ND;
    const bf16* hsrc = hM + (size_t)b * ND * NN;
    const int nbeg = ns * (NN / SPL);
    const int nend = nbeg + NN / SPL;
    for (int n1 = nbeg; n1 < nend; n1 += 64) {
        __syncthreads();
        *reinterpret_cast<bf16x8*>(&fL[s_nl * 80 + s_dl * 2]) =
            *reinterpret_cast<const bf16x8*>(fsrc + (size_t)(n1 + s_nl) * ND + s_dl);
        *reinterpret_cast<bf16x8*>(&hL[s_d * 144 + s_ne * 2]) =
            *reinterpret_cast<const bf16x8*>(hsrc + (size_t)s_d * NN + n1 + s_ne);
        if (t < 64) {
            float s = 0.f;
            #pragma unroll
            for (int ms = 0; ms < SPL; ++ms)
                s += Lpart[((size_t)ms * NB + b) * NN + n1 + t];
            rlL[t] = 1.0f / s;
        }
        __syncthreads();
        #pragma unroll
        for (int nt = 0; nt < 4; ++nt) {
            bf16x8 afrag = *reinterpret_cast<const bf16x8*>(
                &fL[(nt * 16 + l15) * 80 + l4 * 16]);
            f32x4 z = {0.f, 0.f, 0.f, 0.f};
            f32x4 s = __builtin_amdgcn_mfma_f32_16x16x32_bf16(afrag, gfrag, z, 0, 0, 0);
            bf16x4 p4;
            #pragma unroll
            for (int r = 0; r < 4; ++r)
                p4[r] = (bf16)(__expf(s[r]) * rlL[nt * 16 + l4 * 4 + r]);
            *reinterpret_cast<bf16x4*>(
                &Pw[l15 * 128 + ((nt * 32 + l4 * 8) ^ mswz)]) = p4;
        }
        #pragma unroll
        for (int kc = 0; kc < 2; ++kc) {
            bf16x8 pb = *reinterpret_cast<const bf16x8*>(
                &Pw[l15 * 128 + ((kc * 64 + l4 * 16) ^ mswz)]);
            bf16x8 h0 = *reinterpret_cast<const bf16x8*>(
                &hL[l15 * 144 + kc * 64 + l4 * 16]);
            acc0 = __builtin_amdgcn_mfma_f32_16x16x32_bf16(h0, pb, acc0, 0, 0, 0);
            bf16x8 h1 = *reinterpret_cast<const bf16x8*>(
                &hL[(16 + l15) * 144 + kc * 64 + l4 * 16]);
            acc1 = __builtin_amdgcn_mfma_f32_16x16x32_bf16(h1, pb, acc1, 0, 0, 0);
        }
    }
    float* sp = saWS + (((size_t)ns * NB + b) * NN + m0 + w * 16 + l15) * ND;
    *reinterpret_cast<f32x4*>(sp + l4 * 4)      = acc0;
    *reinterpret_cast<f32x4*>(sp + 16 + l4 * 4) = acc1;
}

__global__ __launch_bounds__(256) void k_proj(
    const float* __restrict__ saWS,
    const float* __restrict__ Wv, const float* __restrict__ bv,
    const float* __restrict__ gamma, float* __restrict__ out)
{
    __shared__ float sa_s[64 * 33];
    const int b  = blockIdx.z;
    const int c0 = blockIdx.y * 64;
    const int m0 = blockIdx.x * 64;
    const int t  = threadIdx.x;
    #pragma unroll
    for (int p = t; p < 64 * 8; p += 256) {
        int m = p >> 3, dq = (p & 7) * 4;
        float s0 = 0.f, s1 = 0.f, s2 = 0.f, s3 = 0.f;
        #pragma unroll
        for (int s4 = 0; s4 < SPL; ++s4) {
            f32x4 v = *reinterpret_cast<const f32x4*>(
                saWS + (((size_t)s4 * NB + b) * NN + m0 + m) * ND + dq);
            s0 += v[0]; s1 += v[1]; s2 += v[2]; s3 += v[3];
        }
        float* dp = &sa_s[m * 33 + dq];
        dp[0] = s0; dp[1] = s1; dp[2] = s2; dp[3] = s3;
    }
    __syncthreads();
    const int mloc = t & 63;
    const int cg_  = t >> 6;
    float sav[32];
    #pragma unroll
    for (int d = 0; d < 32; ++d) sav[d] = sa_s[mloc * 33 + d];
    const float g0 = gamma[0];
    float* op = out + (size_t)b * NC * NN + m0 + mloc;
    #pragma unroll
    for (int i = 0; i < 16; ++i) {
        int c = c0 + cg_ * 16 + i;
        const float* wp = Wv + c * ND;
        float sum = bv[c];
        #pragma unroll
        for (int d = 0; d < 32; ++d) sum = fmaf(wp[d], sav[d], sum);
        op[(size_t)c * NN] = g0 * sum;
    }
}

// ---------------------------------------------------------------------------
extern "C" void kernel_launch(void* const* d_in, const int* in_sizes, int n_in,
                              void* d_out, int out_size, void* d_ws, size_t ws_size,
                              hipStream_t stream)
{
    const float* x   = (const float*)d_in[0];
    const float* Wf  = (const float*)d_in[1];
    const float* bfp = (const float*)d_in[2];
    const float* Wg  = (const float*)d_in[3];
    const float* bgp = (const float*)d_in[4];
    const float* Wh  = (const float*)d_in[5];
    const float* bhp = (const float*)d_in[6];
    const float* Wv  = (const float*)d_in[7];
    const float* bv  = (const float*)d_in[8];
    const float* gm  = (const float*)d_in[9];
    float* outp = (float*)d_out;

    char* ws = (char*)d_ws;
    bf16*  Wstk  = (bf16*)ws;                                  // 48 KB (fallback only)
    bf16*  fT    = (bf16*)(ws + 49152);                        // 1 MB
    bf16*  gT    = (bf16*)(ws + 49152 + (1u << 20));           // 1 MB
    bf16*  hM    = (bf16*)(ws + 49152 + (2u << 20));           // 1 MB
    float* Lpart = (float*)(ws + 49152 + (3u << 20));          // 256 KB
    float* saWS  = (float*)(ws + 49152 + (3u << 20) + (256u << 10)); // 8 MB

    void* args[] = {
        (void*)&x, (void*)&Wf, (void*)&bfp, (void*)&Wg, (void*)&bgp,
        (void*)&Wh, (void*)&bhp, (void*)&Wv, (void*)&bv, (void*)&gm,
        (void*)&fT, (void*)&gT, (void*)&hM, (void*)&Lpart, (void*)&saWS,
        (void*)&outp
    };
    hipError_t cerr = hipLaunchCooperativeKernel((const void*)k_mega,
                                                 dim3(GRID), dim3(256),
                                                 args, 0, stream);
    if (cerr != hipSuccess) {
        (void)hipGetLastError();   // clear sticky error, use proven pipeline
        k_wcvt  <<<dim3(12),            dim3(256), 0, stream>>>(Wf, Wg, Wh, Wstk);
        k_fgh   <<<dim3(64, NB),        dim3(512), 0, stream>>>(x, Wstk, bfp, bgp, bhp, fT, gT, hM);
        k_rowsum<<<dim3(64, SPL, NB),   dim3(256), 0, stream>>>(fT, gT, Lpart);
        k_attn  <<<dim3(64, SPL, NB),   dim3(256), 0, stream>>>(fT, gT, hM, Lpart, saWS);
        k_proj  <<<dim3(64, 4, NB),     dim3(256), 0, stream>>>(saWS, Wv, bv, gm, outp);
    }
}

// Round 7
// 179.349 us; speedup vs baseline: 3.2406x; 3.2406x over previous
//
#include <hip/hip_runtime.h>

typedef __bf16 bf16;
typedef bf16 bf16x4 __attribute__((ext_vector_type(4)));
typedef bf16 bf16x8 __attribute__((ext_vector_type(8)));
typedef float f32x4 __attribute__((ext_vector_type(4)));

#define NB 4
#define NC 256
#define ND 32
#define NN 4096
#define MSPLIT 8   // rowsum: m-chunk split across blocks

// ---------------------------------------------------------------------------
// Kernel 1: f/g/h = W @ x (1x1 convs). W converted fp32->bf16 inline
// (validated in the R6 mega run). 32-n tile, 256 thr, grid (256, B) = 1024
// blocks = 4/CU. Outputs fT,gT [B][N][D]; hM [B][D][N] (bf16).
// ---------------------------------------------------------------------------
__global__ __launch_bounds__(256, 4) void k_fgh(
    const float* __restrict__ x,
    const float* __restrict__ Wf, const float* __restrict__ bfp,
    const float* __restrict__ Wg, const float* __restrict__ bgp,
    const float* __restrict__ Wh, const float* __restrict__ bhp,
    bf16* __restrict__ fT, bf16* __restrict__ gT, bf16* __restrict__ hM)
{
    __shared__ __align__(16) char xb[32 * 512];  // [n][c] bf16, XOR-swizzled
    const int b    = blockIdx.y;
    const int rest = blockIdx.x;
    const int n0   = (rest >> 1) * 32;           // 128 n-tiles of 32
    const int half = rest & 1;                   // row-tiles 3*half..3*half+2
    const int t    = threadIdx.x;
    const int lane = t & 63;
    const int w    = t >> 6;
    const int l15  = lane & 15;
    const int l4   = lane >> 4;

    // stage x[b][:, n0:n0+32] -> LDS [n][c] bf16 (swizzled)
    {
        const int nl  = t & 31;
        const int swz = (nl & 7) << 4;
        const int chi = (t >> 5) * 8;            // 0..56
        #pragma unroll
        for (int pass = 0; pass < 4; ++pass) {
            int c0 = pass * 64 + chi;
            const float* xp = x + ((size_t)b * NC + c0) * NN + n0 + nl;
            bf16x8 v;
            #pragma unroll
            for (int j = 0; j < 8; ++j) v[j] = (bf16)xp[(size_t)j * NN];
            *reinterpret_cast<bf16x8*>(&xb[nl * 512 + ((c0 * 2) ^ swz)]) = v;
        }
    }
    __syncthreads();

    #pragma unroll
    for (int rep = 0; rep < 2; ++rep) {
        int tk = w + 4 * rep;                    // 6 tasks: 2 n-strips x 3 rt
        if (tk < 6) {
            const int strip  = tk & 1;
            const int rt     = half * 3 + (tk >> 1);   // 0..5
            const int tensor = rt >> 1;                // 0 f, 1 g, 2 h
            const float* Wsel = tensor == 0 ? Wf : tensor == 1 ? Wg : Wh;
            const float* bsel = tensor == 0 ? bfp : tensor == 1 ? bgp : bhp;
            const int drow = (rt & 1) * 16 + l15;
            const int ncol = strip * 16 + l15;
            const int nswz = (ncol & 7) << 4;
            f32x4 acc = {0.f, 0.f, 0.f, 0.f};
            #pragma unroll
            for (int kc = 0; kc < 8; ++kc) {
                const float* wp = Wsel + drow * NC + kc * 32 + l4 * 8;
                f32x4 wlo = *reinterpret_cast<const f32x4*>(wp);
                f32x4 whi = *reinterpret_cast<const f32x4*>(wp + 4);
                bf16x8 a;
                #pragma unroll
                for (int j = 0; j < 4; ++j) {
                    a[j]     = (bf16)wlo[j];
                    a[4 + j] = (bf16)whi[j];
                }
                bf16x8 bb = *reinterpret_cast<const bf16x8*>(
                    &xb[ncol * 512 + ((kc * 64 + l4 * 16) ^ nswz)]);
                acc = __builtin_amdgcn_mfma_f32_16x16x32_bf16(a, bb, acc, 0, 0, 0);
            }
            const int dbase = (rt & 1) * 16 + l4 * 4;
            const int n = n0 + ncol;
            if (tensor < 2) {
                bf16x4 vv;
                #pragma unroll
                for (int r = 0; r < 4; ++r) vv[r] = (bf16)(acc[r] + bsel[dbase + r]);
                bf16* dst = (tensor == 0 ? fT : gT) + ((size_t)b * NN + n) * ND + dbase;
                *reinterpret_cast<bf16x4*>(dst) = vv;
            } else {
                #pragma unroll
                for (int r = 0; r < 4; ++r)
                    hM[((size_t)b * ND + dbase + r) * NN + n] =
                        (bf16)(acc[r] + bsel[dbase + r]);
            }
        }
    }
}

// ---------------------------------------------------------------------------
// Kernel 2: partial L[n] = sum over an m-chunk of exp(S[n,m]).
// Grid (64 n-tiles, MSPLIT, B) = 2048 blocks. (validated R2 kernel)
// ---------------------------------------------------------------------------
__global__ __launch_bounds__(256) void k_rowsum(
    const bf16* __restrict__ fT, const bf16* __restrict__ gT,
    float* __restrict__ Lpart)
{
    const int b  = blockIdx.z;
    const int ms = blockIdx.y;
    const int nb = blockIdx.x * 64;
    const int t  = threadIdx.x;
    const int lane = t & 63;
    const int w  = t >> 6;
    const int l15 = lane & 15;
    const int l4  = lane >> 4;

    bf16x8 a = *reinterpret_cast<const bf16x8*>(
        fT + ((size_t)b * NN + nb + w * 16 + l15) * ND + l4 * 8);
    float sum0 = 0.f, sum1 = 0.f, sum2 = 0.f, sum3 = 0.f;
    const bf16* gp = gT + (size_t)b * NN * ND
                   + ((size_t)ms * (NN / MSPLIT) + l15) * ND + l4 * 8;
    #pragma unroll 4
    for (int m = 0; m < NN / MSPLIT; m += 32) {
        bf16x8 b0 = *reinterpret_cast<const bf16x8*>(gp + (size_t)m * ND);
        bf16x8 b1 = *reinterpret_cast<const bf16x8*>(gp + (size_t)(m + 16) * ND);
        f32x4 z = {0.f, 0.f, 0.f, 0.f};
        f32x4 s0 = __builtin_amdgcn_mfma_f32_16x16x32_bf16(a, b0, z, 0, 0, 0);
        f32x4 s1 = __builtin_amdgcn_mfma_f32_16x16x32_bf16(a, b1, z, 0, 0, 0);
        sum0 += __expf(s0[0]) + __expf(s1[0]);
        sum1 += __expf(s0[1]) + __expf(s1[1]);
        sum2 += __expf(s0[2]) + __expf(s1[2]);
        sum3 += __expf(s0[3]) + __expf(s1[3]);
    }
    float sv[4] = {sum0, sum1, sum2, sum3};
    #pragma unroll
    for (int r = 0; r < 4; ++r) {
        float v = sv[r];
        v += __shfl_xor(v, 1);
        v += __shfl_xor(v, 2);
        v += __shfl_xor(v, 4);
        v += __shfl_xor(v, 8);
        sv[r] = v;
    }
    if (l15 == 0) {
        #pragma unroll
        for (int r = 0; r < 4; ++r)
            Lpart[((size_t)ms * NB + b) * NN + nb + w * 16 + l4 * 4 + r] = sv[r];
    }
}

// ---------------------------------------------------------------------------
// Kernel 3: fused attention + projection. Block = 16 m-columns, 4 waves.
// Each wave streams disjoint 64-n chunks with NO barriers: f/h fragments
// read straight from L2-resident fT/hM; rl computed inline from Lpart into
// wave-private LDS (per-wave DS FIFO order makes this safe barrier-free);
// sa accumulated in AGPRs. One barrier, then cross-wave reduce + Wv proj.
// Grid (256 m-tiles, B) = 1024 blocks = 4/CU.
// ---------------------------------------------------------------------------
__global__ __launch_bounds__(256, 4) void k_attnproj(
    const bf16* __restrict__ fT, const bf16* __restrict__ gT,
    const bf16* __restrict__ hM, const float* __restrict__ Lpart,
    const float* __restrict__ Wv, const float* __restrict__ bv,
    const float* __restrict__ gamma, float* __restrict__ out)
{
    __shared__ __align__(16) char Pl[4 * 2048];  // per-wave P [16 m][64 n] bf16
    __shared__ float rlw[4][64];                 // per-wave 1/L for current chunk
    __shared__ float sa_s[4][32 * 16];           // per-wave sa [d][m] fp32

    const int b  = blockIdx.y;
    const int m0 = blockIdx.x * 16;
    const int t  = threadIdx.x;
    const int lane = t & 63;
    const int w  = t >> 6;
    const int l15 = lane & 15;
    const int l4  = lane >> 4;

    // g fragment for the block's 16 m (same for all waves)
    bf16x8 gfrag = *reinterpret_cast<const bf16x8*>(
        gT + ((size_t)b * NN + m0 + l15) * ND + l4 * 8);

    f32x4 acc0 = {0.f, 0.f, 0.f, 0.f};   // sa d 0..15
    f32x4 acc1 = {0.f, 0.f, 0.f, 0.f};   // sa d 16..31

    char* Pw = &Pl[w * 2048];
    const int mswz = (l15 & 7) << 4;
    const bf16* fsrc = fT + (size_t)b * NN * ND;
    const bf16* hsrc = hM + (size_t)b * ND * NN;

    for (int it = 0; it < 16; ++it) {
        const int n1 = it * 256 + w * 64;        // wave-private 64-n chunk

        // rl[n1+lane] = 1 / sum_ms Lpart  (wave-private LDS, no barrier)
        float s = 0.f;
        #pragma unroll
        for (int ms = 0; ms < MSPLIT; ++ms)
            s += Lpart[((size_t)ms * NB + b) * NN + n1 + lane];
        rlw[w][lane] = 1.0f / s;

        // S phase: 4 n-subtiles of 16; P = exp(S)*rl in bf16
        #pragma unroll
        for (int nt = 0; nt < 4; ++nt) {
            bf16x8 afrag = *reinterpret_cast<const bf16x8*>(
                fsrc + (size_t)(n1 + nt * 16 + l15) * ND + l4 * 8);
            f32x4 z = {0.f, 0.f, 0.f, 0.f};
            f32x4 sv = __builtin_amdgcn_mfma_f32_16x16x32_bf16(afrag, gfrag, z, 0, 0, 0);
            bf16x4 p4;
            #pragma unroll
            for (int r = 0; r < 4; ++r)
                p4[r] = (bf16)(__expf(sv[r]) * rlw[w][nt * 16 + l4 * 4 + r]);
            *reinterpret_cast<bf16x4*>(
                &Pw[l15 * 128 + ((nt * 32 + l4 * 8) ^ mswz)]) = p4;
        }
        // PV phase: sa += h @ P  (K = 64 in 2 chunks of 32), h from global
        #pragma unroll
        for (int kc = 0; kc < 2; ++kc) {
            bf16x8 pb = *reinterpret_cast<const bf16x8*>(
                &Pw[l15 * 128 + ((kc * 64 + l4 * 16) ^ mswz)]);
            bf16x8 h0 = *reinterpret_cast<const bf16x8*>(
                hsrc + (size_t)l15 * NN + n1 + kc * 32 + l4 * 8);
            acc0 = __builtin_amdgcn_mfma_f32_16x16x32_bf16(h0, pb, acc0, 0, 0, 0);
            bf16x8 h1 = *reinterpret_cast<const bf16x8*>(
                hsrc + (size_t)(16 + l15) * NN + n1 + kc * 32 + l4 * 8);
            acc1 = __builtin_amdgcn_mfma_f32_16x16x32_bf16(h1, pb, acc1, 0, 0, 0);
        }
    }

    // cross-wave reduce sa, then projection
    #pragma unroll
    for (int r = 0; r < 4; ++r) {
        sa_s[w][(l4 * 4 + r) * 16 + l15]        = acc0[r];
        sa_s[w][(16 + l4 * 4 + r) * 16 + l15]   = acc1[r];
    }
    __syncthreads();

    const int m  = t & 15;
    const int cb = (t >> 4) * 16;
    float sav[32];
    #pragma unroll
    for (int d = 0; d < 32; ++d)
        sav[d] = sa_s[0][d * 16 + m] + sa_s[1][d * 16 + m]
               + sa_s[2][d * 16 + m] + sa_s[3][d * 16 + m];
    const float g0 = gamma[0];
    float* op = out + (size_t)b * NC * NN + m0 + m;
    #pragma unroll
    for (int i = 0; i < 16; ++i) {
        int c = cb + i;
        const float* wp = Wv + c * ND;
        float sum = bv[c];
        #pragma unroll
        for (int d = 0; d < 32; ++d) sum = fmaf(wp[d], sav[d], sum);
        op[(size_t)c * NN] = g0 * sum;
    }
}

// ---------------------------------------------------------------------------
extern "C" void kernel_launch(void* const* d_in, const int* in_sizes, int n_in,
                              void* d_out, int out_size, void* d_ws, size_t ws_size,
                              hipStream_t stream)
{
    const float* x   = (const float*)d_in[0];
    const float* Wf  = (const float*)d_in[1];
    const float* bfp = (const float*)d_in[2];
    const float* Wg  = (const float*)d_in[3];
    const float* bgp = (const float*)d_in[4];
    const float* Wh  = (const float*)d_in[5];
    const float* bhp = (const float*)d_in[6];
    const float* Wv  = (const float*)d_in[7];
    const float* bv  = (const float*)d_in[8];
    const float* gm  = (const float*)d_in[9];
    float* outp = (float*)d_out;

    char* ws = (char*)d_ws;
    bf16*  fT    = (bf16*)ws;                          // 1 MB
    bf16*  gT    = (bf16*)(ws + (1u << 20));           // 1 MB
    bf16*  hM    = (bf16*)(ws + (2u << 20));           // 1 MB
    float* Lpart = (float*)(ws + (3u << 20));          // 512 KB

    k_fgh     <<<dim3(256, NB),        dim3(256), 0, stream>>>(
        x, Wf, bfp, Wg, bgp, Wh, bhp, fT, gT, hM);
    k_rowsum  <<<dim3(64, MSPLIT, NB), dim3(256), 0, stream>>>(fT, gT, Lpart);
    k_attnproj<<<dim3(256, NB),        dim3(256), 0, stream>>>(
        fT, gT, hM, Lpart, Wv, bv, gm, outp);
}

// Round 8
// 162.916 us; speedup vs baseline: 3.5674x; 1.1009x over previous
//
#include <hip/hip_runtime.h>

typedef __bf16 bf16;
typedef bf16 bf16x4 __attribute__((ext_vector_type(4)));
typedef bf16 bf16x8 __attribute__((ext_vector_type(8)));
typedef float f32x4 __attribute__((ext_vector_type(4)));

#define NB 4
#define NC 256
#define ND 32
#define NN 4096
#define NSPLIT 8   // attn: n-split across blocks
#define MSPLIT 8   // rowsum: m-split across blocks
#define CSPL 8     // proj: c-split across blocks

// ---------------------------------------------------------------------------
// Kernel 1: f/g/h = W @ x (1x1 convs), W converted fp32->bf16 inline.
// 32-n tile, grid (256, B) = 1024 blocks. fT,gT [B][N][D]; hM [B][D][N].
// ---------------------------------------------------------------------------
__global__ __launch_bounds__(256, 4) void k_fgh(
    const float* __restrict__ x,
    const float* __restrict__ Wf, const float* __restrict__ bfp,
    const float* __restrict__ Wg, const float* __restrict__ bgp,
    const float* __restrict__ Wh, const float* __restrict__ bhp,
    bf16* __restrict__ fT, bf16* __restrict__ gT, bf16* __restrict__ hM)
{
    __shared__ __align__(16) char xb[32 * 512];  // [n][c] bf16, XOR-swizzled
    const int b    = blockIdx.y;
    const int rest = blockIdx.x;
    const int n0   = (rest >> 1) * 32;
    const int half = rest & 1;
    const int t    = threadIdx.x;
    const int lane = t & 63;
    const int w    = t >> 6;
    const int l15  = lane & 15;
    const int l4   = lane >> 4;

    {
        const int nl  = t & 31;
        const int swz = (nl & 7) << 4;
        const int chi = (t >> 5) * 8;
        #pragma unroll
        for (int pass = 0; pass < 4; ++pass) {
            int c0 = pass * 64 + chi;
            const float* xp = x + ((size_t)b * NC + c0) * NN + n0 + nl;
            bf16x8 v;
            #pragma unroll
            for (int j = 0; j < 8; ++j) v[j] = (bf16)xp[(size_t)j * NN];
            *reinterpret_cast<bf16x8*>(&xb[nl * 512 + ((c0 * 2) ^ swz)]) = v;
        }
    }
    __syncthreads();

    #pragma unroll
    for (int rep = 0; rep < 2; ++rep) {
        int tk = w + 4 * rep;                    // 6 tasks: 2 n-strips x 3 rt
        if (tk < 6) {
            const int strip  = tk & 1;
            const int rt     = half * 3 + (tk >> 1);
            const int tensor = rt >> 1;
            const float* Wsel = tensor == 0 ? Wf : tensor == 1 ? Wg : Wh;
            const float* bsel = tensor == 0 ? bfp : tensor == 1 ? bgp : bhp;
            const int drow = (rt & 1) * 16 + l15;
            const int ncol = strip * 16 + l15;
            const int nswz = (ncol & 7) << 4;
            f32x4 acc = {0.f, 0.f, 0.f, 0.f};
            #pragma unroll
            for (int kc = 0; kc < 8; ++kc) {
                const float* wp = Wsel + drow * NC + kc * 32 + l4 * 8;
                f32x4 wlo = *reinterpret_cast<const f32x4*>(wp);
                f32x4 whi = *reinterpret_cast<const f32x4*>(wp + 4);
                bf16x8 a;
                #pragma unroll
                for (int j = 0; j < 4; ++j) {
                    a[j]     = (bf16)wlo[j];
                    a[4 + j] = (bf16)whi[j];
                }
                bf16x8 bb = *reinterpret_cast<const bf16x8*>(
                    &xb[ncol * 512 + ((kc * 64 + l4 * 16) ^ nswz)]);
                acc = __builtin_amdgcn_mfma_f32_16x16x32_bf16(a, bb, acc, 0, 0, 0);
            }
            const int dbase = (rt & 1) * 16 + l4 * 4;
            const int n = n0 + ncol;
            if (tensor < 2) {
                bf16x4 vv;
                #pragma unroll
                for (int r = 0; r < 4; ++r) vv[r] = (bf16)(acc[r] + bsel[dbase + r]);
                bf16* dst = (tensor == 0 ? fT : gT) + ((size_t)b * NN + n) * ND + dbase;
                *reinterpret_cast<bf16x4*>(dst) = vv;
            } else {
                #pragma unroll
                for (int r = 0; r < 4; ++r)
                    hM[((size_t)b * ND + dbase + r) * NN + n] =
                        (bf16)(acc[r] + bsel[dbase + r]);
            }
        }
    }
}

// ---------------------------------------------------------------------------
// Kernel 2: partial L[n] = sum over an m-chunk of exp(S[n,m]).
// Grid (64, MSPLIT, B) = 2048 blocks. (R4-proven, unchanged)
// ---------------------------------------------------------------------------
__global__ __launch_bounds__(256) void k_rowsum(
    const bf16* __restrict__ fT, const bf16* __restrict__ gT,
    float* __restrict__ Lpart)
{
    const int b  = blockIdx.z;
    const int ms = blockIdx.y;
    const int nb = blockIdx.x * 64;
    const int t  = threadIdx.x;
    const int lane = t & 63;
    const int w  = t >> 6;
    const int l15 = lane & 15;
    const int l4  = lane >> 4;

    bf16x8 a = *reinterpret_cast<const bf16x8*>(
        fT + ((size_t)b * NN + nb + w * 16 + l15) * ND + l4 * 8);
    float sum0 = 0.f, sum1 = 0.f, sum2 = 0.f, sum3 = 0.f;
    const bf16* gp = gT + (size_t)b * NN * ND
                   + ((size_t)ms * (NN / MSPLIT) + l15) * ND + l4 * 8;
    #pragma unroll 4
    for (int m = 0; m < NN / MSPLIT; m += 32) {
        bf16x8 b0 = *reinterpret_cast<const bf16x8*>(gp + (size_t)m * ND);
        bf16x8 b1 = *reinterpret_cast<const bf16x8*>(gp + (size_t)(m + 16) * ND);
        f32x4 z = {0.f, 0.f, 0.f, 0.f};
        f32x4 s0 = __builtin_amdgcn_mfma_f32_16x16x32_bf16(a, b0, z, 0, 0, 0);
        f32x4 s1 = __builtin_amdgcn_mfma_f32_16x16x32_bf16(a, b1, z, 0, 0, 0);
        sum0 += __expf(s0[0]) + __expf(s1[0]);
        sum1 += __expf(s0[1]) + __expf(s1[1]);
        sum2 += __expf(s0[2]) + __expf(s1[2]);
        sum3 += __expf(s0[3]) + __expf(s1[3]);
    }
    float sv[4] = {sum0, sum1, sum2, sum3};
    #pragma unroll
    for (int r = 0; r < 4; ++r) {
        float v = sv[r];
        v += __shfl_xor(v, 1);
        v += __shfl_xor(v, 2);
        v += __shfl_xor(v, 4);
        v += __shfl_xor(v, 8);
        sv[r] = v;
    }
    if (l15 == 0) {
        #pragma unroll
        for (int r = 0; r < 4; ++r)
            Lpart[((size_t)ms * NB + b) * NN + nb + w * 16 + l4 * 4 + r] = sv[r];
    }
}

// ---------------------------------------------------------------------------
// Kernel 3: partial sa[d,m] over an n-chunk, DOUBLE-BUFFERED staging:
// one barrier/iter; next tile's f/h/Lpart loads issued right after the
// barrier so L2 latency hides under S+PV compute. Grid (64, NSPLIT, B).
// ---------------------------------------------------------------------------
__global__ __launch_bounds__(256) void k_attn(
    const bf16* __restrict__ fT, const bf16* __restrict__ gT,
    const bf16* __restrict__ hM, const float* __restrict__ Lpart,
    float* __restrict__ saWS)
{
    __shared__ __align__(16) char fL[2][64 * 80];   // [n][d] bf16, 80B rows
    __shared__ __align__(16) char hL[2][32 * 144];  // [d][n] bf16, 144B rows
    __shared__ __align__(16) char Pl[4 * 2048];     // per-wave P, swizzled
    __shared__ float rlL[2][64];

    const int b  = blockIdx.z;
    const int ns = blockIdx.y;
    const int m0 = blockIdx.x * 64;
    const int t  = threadIdx.x;
    const int lane = t & 63;
    const int w  = t >> 6;
    const int l15 = lane & 15;
    const int l4  = lane >> 4;

    bf16x8 gfrag = *reinterpret_cast<const bf16x8*>(
        gT + ((size_t)b * NN + m0 + w * 16 + l15) * ND + l4 * 8);

    f32x4 acc0 = {0.f, 0.f, 0.f, 0.f};   // sa d 0..15
    f32x4 acc1 = {0.f, 0.f, 0.f, 0.f};   // sa d 16..31

    char* Pw = &Pl[w * 2048];
    const int mswz = (l15 & 7) << 4;

    const int s_nl = t >> 2;             // f staging: 64 rows x 64B
    const int s_dl = (t & 3) * 8;
    const int s_d  = t >> 3;             // h staging: 32 rows x 128B
    const int s_ne = (t & 7) * 8;
    const bf16* fsrc = fT + (size_t)b * NN * ND;
    const bf16* hsrc = hM + (size_t)b * ND * NN;

    const int nbeg = ns * (NN / NSPLIT);

    // prologue: load tile 0 into regs
    bf16x8 fv = *reinterpret_cast<const bf16x8*>(
        fsrc + (size_t)(nbeg + s_nl) * ND + s_dl);
    bf16x8 hv = *reinterpret_cast<const bf16x8*>(
        hsrc + (size_t)s_d * NN + nbeg + s_ne);
    float lsum = 0.f;
    if (t < 64) {
        #pragma unroll
        for (int ms = 0; ms < MSPLIT; ++ms)
            lsum += Lpart[((size_t)ms * NB + b) * NN + nbeg + t];
    }

    #pragma unroll 2
    for (int it = 0; it < NN / NSPLIT / 64; ++it) {
        const int cur = it & 1;
        const int n1  = nbeg + it * 64;

        // write current regs -> LDS[cur]
        *reinterpret_cast<bf16x8*>(&fL[cur][s_nl * 80 + s_dl * 2]) = fv;
        *reinterpret_cast<bf16x8*>(&hL[cur][s_d * 144 + s_ne * 2]) = hv;
        if (t < 64) rlL[cur][t] = 1.0f / lsum;
        __syncthreads();

        // issue next tile's loads (overlap with compute below)
        if (it + 1 < NN / NSPLIT / 64) {
            const int n2 = n1 + 64;
            fv = *reinterpret_cast<const bf16x8*>(
                fsrc + (size_t)(n2 + s_nl) * ND + s_dl);
            hv = *reinterpret_cast<const bf16x8*>(
                hsrc + (size_t)s_d * NN + n2 + s_ne);
            if (t < 64) {
                float s = 0.f;
                #pragma unroll
                for (int ms = 0; ms < MSPLIT; ++ms)
                    s += Lpart[((size_t)ms * NB + b) * NN + n2 + t];
                lsum = s;
            }
        }

        // S phase: P = exp(S)*rl in bf16 (wave-private strip)
        #pragma unroll
        for (int nt = 0; nt < 4; ++nt) {
            bf16x8 afrag = *reinterpret_cast<const bf16x8*>(
                &fL[cur][(nt * 16 + l15) * 80 + l4 * 16]);
            f32x4 z = {0.f, 0.f, 0.f, 0.f};
            f32x4 s = __builtin_amdgcn_mfma_f32_16x16x32_bf16(afrag, gfrag, z, 0, 0, 0);
            bf16x4 p4;
            #pragma unroll
            for (int r = 0; r < 4; ++r)
                p4[r] = (bf16)(__expf(s[r]) * rlL[cur][nt * 16 + l4 * 4 + r]);
            *reinterpret_cast<bf16x4*>(
                &Pw[l15 * 128 + ((nt * 32 + l4 * 8) ^ mswz)]) = p4;
        }
        // PV phase: sa += h @ P  (K = 64 in 2 chunks of 32)
        #pragma unroll
        for (int kc = 0; kc < 2; ++kc) {
            bf16x8 pb = *reinterpret_cast<const bf16x8*>(
                &Pw[l15 * 128 + ((kc * 64 + l4 * 16) ^ mswz)]);
            bf16x8 h0 = *reinterpret_cast<const bf16x8*>(
                &hL[cur][l15 * 144 + kc * 64 + l4 * 16]);
            acc0 = __builtin_amdgcn_mfma_f32_16x16x32_bf16(h0, pb, acc0, 0, 0, 0);
            bf16x8 h1 = *reinterpret_cast<const bf16x8*>(
                &hL[cur][(16 + l15) * 144 + kc * 64 + l4 * 16]);
            acc1 = __builtin_amdgcn_mfma_f32_16x16x32_bf16(h1, pb, acc1, 0, 0, 0);
        }
    }

    float* sp = saWS + (((size_t)ns * NB + b) * NN + m0 + w * 16 + l15) * ND;
    *reinterpret_cast<f32x4*>(sp + l4 * 4)      = acc0;
    *reinterpret_cast<f32x4*>(sp + 16 + l4 * 4) = acc1;
}

// ---------------------------------------------------------------------------
// Kernel 4: reduce sa partials + projection. Grid (64, CSPL, B) = 2048.
// (R4-proven, unchanged)
// ---------------------------------------------------------------------------
__global__ __launch_bounds__(256) void k_proj(
    const float* __restrict__ saWS,
    const float* __restrict__ Wv, const float* __restrict__ bv,
    const float* __restrict__ gamma, float* __restrict__ out)
{
    __shared__ float sa_s[64 * 33];
    const int b  = blockIdx.z;
    const int c0 = blockIdx.y * (NC / CSPL);   // 32 c per block
    const int m0 = blockIdx.x * 64;
    const int t  = threadIdx.x;

    #pragma unroll
    for (int p = t; p < 64 * 8; p += 256) {
        int m = p >> 3, dq = (p & 7) * 4;
        float s0 = 0.f, s1 = 0.f, s2 = 0.f, s3 = 0.f;
        #pragma unroll
        for (int s4 = 0; s4 < NSPLIT; ++s4) {
            f32x4 v = *reinterpret_cast<const f32x4*>(
                saWS + (((size_t)s4 * NB + b) * NN + m0 + m) * ND + dq);
            s0 += v[0]; s1 += v[1]; s2 += v[2]; s3 += v[3];
        }
        float* dp = &sa_s[m * 33 + dq];
        dp[0] = s0; dp[1] = s1; dp[2] = s2; dp[3] = s3;
    }
    __syncthreads();

    const int mloc = t & 63;
    const int cg   = t >> 6;             // wave-uniform c-group
    float sav[32];
    #pragma unroll
    for (int d = 0; d < 32; ++d) sav[d] = sa_s[mloc * 33 + d];
    const float g0 = gamma[0];
    float* op = out + (size_t)b * NC * NN + m0 + mloc;
    #pragma unroll
    for (int i = 0; i < 8; ++i) {
        int c = c0 + cg * 8 + i;
        const float* wp = Wv + c * ND;
        float sum = bv[c];
        #pragma unroll
        for (int d = 0; d < 32; ++d) sum = fmaf(wp[d], sav[d], sum);
        op[(size_t)c * NN] = g0 * sum;
    }
}

// ---------------------------------------------------------------------------
extern "C" void kernel_launch(void* const* d_in, const int* in_sizes, int n_in,
                              void* d_out, int out_size, void* d_ws, size_t ws_size,
                              hipStream_t stream)
{
    const float* x   = (const float*)d_in[0];
    const float* Wf  = (const float*)d_in[1];
    const float* bfp = (const float*)d_in[2];
    const float* Wg  = (const float*)d_in[3];
    const float* bgp = (const float*)d_in[4];
    const float* Wh  = (const float*)d_in[5];
    const float* bhp = (const float*)d_in[6];
    const float* Wv  = (const float*)d_in[7];
    const float* bv  = (const float*)d_in[8];
    const float* gm  = (const float*)d_in[9];
    float* outp = (float*)d_out;

    char* ws = (char*)d_ws;
    bf16*  fT    = (bf16*)ws;                          // 1 MB
    bf16*  gT    = (bf16*)(ws + (1u << 20));           // 1 MB
    bf16*  hM    = (bf16*)(ws + (2u << 20));           // 1 MB
    float* Lpart = (float*)(ws + (3u << 20));          // 512 KB
    float* saWS  = (float*)(ws + (3u << 20) + (512u << 10)); // 16 MB

    k_fgh   <<<dim3(256, NB),        dim3(256), 0, stream>>>(
        x, Wf, bfp, Wg, bgp, Wh, bhp, fT, gT, hM);
    k_rowsum<<<dim3(64, MSPLIT, NB), dim3(256), 0, stream>>>(fT, gT, Lpart);
    k_attn  <<<dim3(64, NSPLIT, NB), dim3(256), 0, stream>>>(fT, gT, hM, Lpart, saWS);
    k_proj  <<<dim3(64, CSPL, NB),   dim3(256), 0, stream>>>(saWS, Wv, bv, gm, outp);
}